// Round 12
// baseline (341.918 us; speedup 1.0000x reference)
//
#include <hip/hip_runtime.h>
#include <math.h>

#define D_ 256
#define NL_ 4
#define NC_ 2
#define L_LEN 1024
#define NSTATE_ 64
#define DIN_ 512
#define H_ 8
#define P_ 64
#define CONVDIM_ 640
#define DPROJ_ 1160
#define EPS_ 1e-5f
#define NCH_ 16

typedef __attribute__((ext_vector_type(8))) short short8;
typedef __attribute__((ext_vector_type(4))) float f32x4;
typedef __attribute__((ext_vector_type(4))) unsigned short us4;

__device__ __forceinline__ float siluf(float x) { return x / (1.f + __expf(-x)); }
__device__ __forceinline__ float geluf(float x) { return 0.5f * x * (1.f + erff(x * 0.70710678118654752f)); }
__device__ __forceinline__ unsigned short f2bf(float f) {
    unsigned u = __float_as_uint(f);
    u += 0x7FFFu + ((u >> 16) & 1u);
    return (unsigned short)(u >> 16);
}
__device__ __forceinline__ float bf2f(unsigned short h) {
    return __uint_as_float(((unsigned)h) << 16);
}

// merged prep — weight splits + embed in ONE dispatch.
__global__ void k_prep(const float* __restrict__ Wi, const float* __restrict__ Wo,
                       const float* __restrict__ nw,
                       unsigned short* __restrict__ wih, unsigned short* __restrict__ wil,
                       unsigned short* __restrict__ woh, unsigned short* __restrict__ wol,
                       const int* __restrict__ ids, const float* __restrict__ emb,
                       const float* __restrict__ pos, float* __restrict__ x,
                       int nin, int nout, int nemb) {
    int i = blockIdx.x * blockDim.x + threadIdx.x;
    if (i < nin) {
        float f = Wi[i];
        unsigned short h = f2bf(f);
        wih[i] = h;
        wil[i] = f2bf(f - bf2f(h));
    } else if (i < nin + nout) {
        int j = i - nin;
        int layer = j / (D_ * DIN_);
        int k = j % DIN_;
        float f = Wo[j] * nw[layer * DIN_ + k];
        unsigned short h = f2bf(f);
        woh[j] = h;
        wol[j] = f2bf(f - bf2f(h));
    } else if (i < nin + nout + nemb) {
        int k = i - nin - nout;
        int d = k & (D_ - 1);
        int bl = k >> 8;
        int l = bl & (L_LEN - 1);
        x[k] = emb[ids[bl] * D_ + d] + pos[l * D_ + d];
    }
}

// in-proj: zx[M,N] = x[M,K] @ Win^T.  R7 math; R25: XCD-grouping remap
// (nwg=608, q=76: orig=(lin%8)*76+lin/8, bx-major decompose) so the 32 blocks
// sharing one B panel (64KB) co-locate on an XCD. Bijective, bit-identical.
__global__ void __launch_bounds__(256) gemm_in(const float* __restrict__ A,
        const unsigned short* __restrict__ Bhi, const unsigned short* __restrict__ Blo,
        float* __restrict__ C, int M, int N, int K) {
    __shared__ __align__(16) unsigned short Ah[64 * 72];
    __shared__ __align__(16) unsigned short Al[64 * 72];
    __shared__ __align__(16) unsigned short Bh[64 * 72];
    __shared__ __align__(16) unsigned short Bl[64 * 72];
    const int tid = threadIdx.x;
    const int lin = blockIdx.x + 19 * blockIdx.y;   // 0..607
    const int orig = (lin & 7) * 76 + (lin >> 3);   // bijective (608 = 8*76)
    const int bx = orig >> 5;                       // /32: 0..18
    const int by = orig & 31;                       // %32
    const int col0 = bx * 64;
    const int row0 = by * 64;

    const int sar = tid >> 2, sas = (tid & 3) * 16;
    const bool bok = (col0 + sar) < N;
    const float* aptr = A + (size_t)(row0 + sar) * K + sas;
    const unsigned short* bhptr = Bhi + (size_t)(col0 + sar) * K + sas;
    const unsigned short* blptr = Blo + (size_t)(col0 + sar) * K + sas;

    float4 pa[4];
#pragma unroll
    for (int i = 0; i < 4; ++i) pa[i] = *(const float4*)(aptr + i * 4);
    short8 pbh0 = {0,0,0,0,0,0,0,0}, pbh1 = {0,0,0,0,0,0,0,0};
    short8 pbl0 = {0,0,0,0,0,0,0,0}, pbl1 = {0,0,0,0,0,0,0,0};
    if (bok) {
        pbh0 = *(const short8*)bhptr; pbh1 = *(const short8*)(bhptr + 8);
        pbl0 = *(const short8*)blptr; pbl1 = *(const short8*)(blptr + 8);
    }

    const int wave = tid >> 6, lane = tid & 63;
    const int lq = lane >> 4, lm = lane & 15;
    f32x4 acc[4] = {};
    const int nsteps = K >> 6;   // BK=64
    for (int s = 0; s < nsteps; ++s) {
        __syncthreads();
#pragma unroll
        for (int i = 0; i < 4; ++i) {
            float4 f = pa[i];
            unsigned short h0 = f2bf(f.x), h1 = f2bf(f.y), h2 = f2bf(f.z), h3 = f2bf(f.w);
            us4 hv = {h0, h1, h2, h3};
            us4 lv = {f2bf(f.x - bf2f(h0)), f2bf(f.y - bf2f(h1)),
                      f2bf(f.z - bf2f(h2)), f2bf(f.w - bf2f(h3))};
            *(us4*)&Ah[sar * 72 + sas + i * 4] = hv;
            *(us4*)&Al[sar * 72 + sas + i * 4] = lv;
        }
        *(short8*)&Bh[sar * 72 + sas] = pbh0;
        *(short8*)&Bh[sar * 72 + sas + 8] = pbh1;
        *(short8*)&Bl[sar * 72 + sas] = pbl0;
        *(short8*)&Bl[sar * 72 + sas + 8] = pbl1;
        __syncthreads();
        if (s + 1 < nsteps) {
            int ko = (s + 1) * 64;
#pragma unroll
            for (int i = 0; i < 4; ++i) pa[i] = *(const float4*)(aptr + ko + i * 4);
            if (bok) {
                pbh0 = *(const short8*)(bhptr + ko); pbh1 = *(const short8*)(bhptr + ko + 8);
                pbl0 = *(const short8*)(blptr + ko); pbl1 = *(const short8*)(blptr + ko + 8);
            }
        }
#pragma unroll
        for (int k32 = 0; k32 < 2; ++k32) {
            const int kof = k32 * 32 + lq * 8;
            short8 bh[4], bl[4];
#pragma unroll
            for (int ct = 0; ct < 4; ++ct) {
                bh[ct] = *(const short8*)&Bh[(ct * 16 + lm) * 72 + kof];
                bl[ct] = *(const short8*)&Bl[(ct * 16 + lm) * 72 + kof];
            }
            short8 ah = *(const short8*)&Ah[(wave * 16 + lm) * 72 + kof];
            short8 al = *(const short8*)&Al[(wave * 16 + lm) * 72 + kof];
#pragma unroll
            for (int ct = 0; ct < 4; ++ct) {
                acc[ct] = __builtin_amdgcn_mfma_f32_16x16x32_bf16(ah, bh[ct], acc[ct], 0, 0, 0);
                acc[ct] = __builtin_amdgcn_mfma_f32_16x16x32_bf16(ah, bl[ct], acc[ct], 0, 0, 0);
                acc[ct] = __builtin_amdgcn_mfma_f32_16x16x32_bf16(al, bh[ct], acc[ct], 0, 0, 0);
            }
        }
    }
#pragma unroll
    for (int ct = 0; ct < 4; ++ct) {
        int col = col0 + ct * 16 + lm;
        if (col >= N) continue;
        int rbase = row0 + wave * 16 + lq * 4;
#pragma unroll
        for (int reg = 0; reg < 4; ++reg) {
            C[(size_t)(rbase + reg) * N + col] = acc[ct][reg];
        }
    }
}

// out-proj: split-K 4, BK=64 (R7/R4 math); R25: XCD-grouping remap (nwg=512,
// q=64, by-major decompose) so the 16 blocks sharing one gh/gl row panel
// (128KB) co-locate. Bijective, bit-identical math.
__global__ void __launch_bounds__(256) gemm_outs(const unsigned short* __restrict__ Ghg,
        const unsigned short* __restrict__ Glg, const float* __restrict__ rowssq,
        const unsigned short* __restrict__ Bhi, const unsigned short* __restrict__ Blo,
        float* __restrict__ x) {
    __shared__ __align__(16) unsigned short Ah[64 * 72];
    __shared__ __align__(16) unsigned short Al[64 * 72];
    __shared__ __align__(16) unsigned short Bh[64 * 72];
    __shared__ __align__(16) unsigned short Bl[64 * 72];
    const int tid = threadIdx.x;
    const int lin = blockIdx.x + 4 * blockIdx.y + 128 * blockIdx.z;  // 0..511
    const int orig = (lin & 7) * 64 + (lin >> 3);   // bijective (512 = 8*64)
    const int by = orig >> 4;                       // /16: 0..31
    const int rem = orig & 15;
    const int bxn = rem >> 2;                       // 0..3
    const int bz = rem & 3;                         // 0..3
    const int col0 = bxn * 64;
    const int row0 = by * 64;
    const int kbase = bz * 128;
    const int sar = tid >> 2, sas = (tid & 3) * 16;
    const unsigned short* ahptr = Ghg + (size_t)(row0 + sar) * DIN_ + kbase + sas;
    const unsigned short* alptr = Glg + (size_t)(row0 + sar) * DIN_ + kbase + sas;
    const unsigned short* bhptr = Bhi + (size_t)(col0 + sar) * DIN_ + kbase + sas;
    const unsigned short* blptr = Blo + (size_t)(col0 + sar) * DIN_ + kbase + sas;

    short8 pah0 = *(const short8*)ahptr, pah1 = *(const short8*)(ahptr + 8);
    short8 pal0 = *(const short8*)alptr, pal1 = *(const short8*)(alptr + 8);
    short8 pbh0 = *(const short8*)bhptr, pbh1 = *(const short8*)(bhptr + 8);
    short8 pbl0 = *(const short8*)blptr, pbl1 = *(const short8*)(blptr + 8);

    const int wave = tid >> 6, lane = tid & 63;
    const int lq = lane >> 4, lm = lane & 15;
    f32x4 acc[4] = {};
    for (int s = 0; s < 2; ++s) {
        __syncthreads();
        *(short8*)&Ah[sar * 72 + sas] = pah0;
        *(short8*)&Ah[sar * 72 + sas + 8] = pah1;
        *(short8*)&Al[sar * 72 + sas] = pal0;
        *(short8*)&Al[sar * 72 + sas + 8] = pal1;
        *(short8*)&Bh[sar * 72 + sas] = pbh0;
        *(short8*)&Bh[sar * 72 + sas + 8] = pbh1;
        *(short8*)&Bl[sar * 72 + sas] = pbl0;
        *(short8*)&Bl[sar * 72 + sas + 8] = pbl1;
        __syncthreads();
        if (s + 1 < 2) {
            int ko = 64;
            pah0 = *(const short8*)(ahptr + ko); pah1 = *(const short8*)(ahptr + ko + 8);
            pal0 = *(const short8*)(alptr + ko); pal1 = *(const short8*)(alptr + ko + 8);
            pbh0 = *(const short8*)(bhptr + ko); pbh1 = *(const short8*)(bhptr + ko + 8);
            pbl0 = *(const short8*)(blptr + ko); pbl1 = *(const short8*)(blptr + ko + 8);
        }
#pragma unroll
        for (int k32 = 0; k32 < 2; ++k32) {
            const int kof = k32 * 32 + lq * 8;
            short8 bh[4], bl[4];
#pragma unroll
            for (int ct = 0; ct < 4; ++ct) {
                bh[ct] = *(const short8*)&Bh[(ct * 16 + lm) * 72 + kof];
                bl[ct] = *(const short8*)&Bl[(ct * 16 + lm) * 72 + kof];
            }
            short8 ah = *(const short8*)&Ah[(wave * 16 + lm) * 72 + kof];
            short8 al = *(const short8*)&Al[(wave * 16 + lm) * 72 + kof];
#pragma unroll
            for (int ct = 0; ct < 4; ++ct) {
                acc[ct] = __builtin_amdgcn_mfma_f32_16x16x32_bf16(ah, bh[ct], acc[ct], 0, 0, 0);
                acc[ct] = __builtin_amdgcn_mfma_f32_16x16x32_bf16(ah, bl[ct], acc[ct], 0, 0, 0);
                acc[ct] = __builtin_amdgcn_mfma_f32_16x16x32_bf16(al, bh[ct], acc[ct], 0, 0, 0);
            }
        }
    }
    {
        int rbase = row0 + wave * 16 + lq * 4;
        float sc[4];
#pragma unroll
        for (int reg = 0; reg < 4; ++reg)
            sc[reg] = rsqrtf(rowssq[rbase + reg] * (1.f / DIN_) + EPS_);
#pragma unroll
        for (int ct = 0; ct < 4; ++ct) {
            int col = col0 + ct * 16 + lm;
#pragma unroll
            for (int reg = 0; reg < 4; ++reg) {
                atomicAdd(&x[(size_t)(rbase + reg) * D_ + col], sc[reg] * acc[ct][reg]);
            }
        }
    }
}

// Fused SSM part A — EXACT R4 version (frozen; natural map already XCD-groups
// same-chunk blocks which share the zx B/C window).
__global__ void __launch_bounds__(512) k_ssmA(const float* __restrict__ zx,
        const float* __restrict__ cw, const float* __restrict__ cb,
        const float* __restrict__ dtbias, const float* __restrict__ Alog,
        const float* __restrict__ Dp,
        float* __restrict__ Sbuf, float* __restrict__ decay,
        float* __restrict__ Ctil, float* __restrict__ y, float* __restrict__ rowssq) {
    __shared__ float U[64][65];
    __shared__ float V[64][65];
    __shared__ float W[64][65];
    __shared__ float sdt[64], cs[64], wj[64];
    const int c = blockIdx.x, bh = blockIdx.y;
    const int b = bh >> 3, h = bh & 7;
    const int l0 = c << 6;
    const int tid = threadIdx.x, wid8 = tid >> 6, lane = tid & 63;

    if (h == 0 && tid < 64) rowssq[b * L_LEN + l0 + tid] = 0.f;

    const int chx = h * P_ + lane;
    const int chb = DIN_ + lane;
    const int chc = DIN_ + NSTATE_ + lane;
    float wx0 = cw[chx * 4], wx1 = cw[chx * 4 + 1], wx2 = cw[chx * 4 + 2], wx3 = cw[chx * 4 + 3];
    float wb0 = cw[chb * 4], wb1 = cw[chb * 4 + 1], wb2 = cw[chb * 4 + 2], wb3 = cw[chb * 4 + 3];
    float wc0 = cw[chc * 4], wc1 = cw[chc * 4 + 1], wc2 = cw[chc * 4 + 2], wc3 = cw[chc * 4 + 3];
    float bx = cb[chx], bb = cb[chb], bc = cb[chc];

    for (int r = 0; r < 64; r += 8) {
        int j = r + wid8;
        int l = l0 + j;
        float ax = bx, ab = bb, ac = bc;
#pragma unroll
        for (int k = 0; k < 4; ++k) {
            int t = l - 3 + k;
            if (t >= 0) {
                const float* row = zx + (size_t)(b * L_LEN + t) * DPROJ_;
                float wxk = (k == 0) ? wx0 : (k == 1) ? wx1 : (k == 2) ? wx2 : wx3;
                float wbk = (k == 0) ? wb0 : (k == 1) ? wb1 : (k == 2) ? wb2 : wb3;
                float wck = (k == 0) ? wc0 : (k == 1) ? wc1 : (k == 2) ? wc2 : wc3;
                ax += wxk * row[DIN_ + chx];
                ab += wbk * row[DIN_ + chb];
                ac += wck * row[DIN_ + chc];
            }
        }
        U[j][lane] = siluf(ax);
        V[j][lane] = siluf(ab);
        W[j][lane] = siluf(ac);
    }
    if (tid < 64) {
        float xv = zx[(size_t)(b * L_LEN + l0 + tid) * DPROJ_ + (DPROJ_ - H_) + h] + dtbias[h];
        float sp = fmaxf(xv, 0.f) + log1pf(__expf(-fabsf(xv)));
        sdt[tid] = sp;
        float v = sp * (-__expf(Alog[h]));
#pragma unroll
        for (int off = 1; off < 64; off <<= 1) {
            float t = __shfl_up(v, off, 64);
            if (tid >= off) v += t;
        }
        cs[tid] = v;
        float tot = __shfl(v, 63, 64);
        wj[tid] = __expf(tot - v) * sp;
        if (tid == 63) decay[bh * NCH_ + c] = __expf(tot);
    }
    __syncthreads();

    const int t4 = (tid & 15) * 4;
    const int r4 = ((tid >> 4) & 15) * 4;
    const size_t sbase = (size_t)(bh * NCH_ + c) * 4096;

    if (tid < 256) {
        float acc[4][4] = {};
        for (int j = 0; j < 64; ++j) {
            float w = wj[j];
            float4 xv = *(const float4*)&U[j][r4];
            float4 bv = *(const float4*)&V[j][t4];
            float xw[4] = {xv.x * w, xv.y * w, xv.z * w, xv.w * w};
#pragma unroll
            for (int ii = 0; ii < 4; ++ii) {
                acc[ii][0] += xw[ii] * bv.x;
                acc[ii][1] += xw[ii] * bv.y;
                acc[ii][2] += xw[ii] * bv.z;
                acc[ii][3] += xw[ii] * bv.w;
            }
        }
#pragma unroll
        for (int ii = 0; ii < 4; ++ii) {
            float4 v = {acc[ii][0], acc[ii][1], acc[ii][2], acc[ii][3]};
            *(float4*)&Sbuf[sbase + (size_t)(r4 + ii) * 64 + t4] = v;
        }
    }
    for (int r = 0; r < 64; r += 8) {
        int ii = r + wid8;
        Ctil[sbase + ii * 64 + lane] = __expf(cs[ii]) * W[ii][lane];
    }
    float wt[4][4];
    if (tid < 256) {
        float g[4][4] = {};
        for (int ng = 0; ng < 64; ng += 4) {
            float4 cf[4], bf[4];
#pragma unroll
            for (int ii = 0; ii < 4; ++ii) cf[ii] = *(const float4*)&W[r4 + ii][ng];
#pragma unroll
            for (int jj = 0; jj < 4; ++jj) bf[jj] = *(const float4*)&V[t4 + jj][ng];
#pragma unroll
            for (int ii = 0; ii < 4; ++ii)
#pragma unroll
                for (int jj = 0; jj < 4; ++jj)
                    g[ii][jj] += cf[ii].x * bf[jj].x + cf[ii].y * bf[jj].y +
                                 cf[ii].z * bf[jj].z + cf[ii].w * bf[jj].w;
        }
#pragma unroll
        for (int ii = 0; ii < 4; ++ii) {
            int i = r4 + ii;
            float csi = cs[i];
#pragma unroll
            for (int jj = 0; jj < 4; ++jj) {
                int j = t4 + jj;
                wt[ii][jj] = (j <= i) ? __expf(fminf(csi - cs[j], 0.f)) * sdt[j] * g[ii][jj] : 0.f;
            }
        }
    }
    __syncthreads();
    if (tid < 256) {
#pragma unroll
        for (int jj = 0; jj < 4; ++jj) {
            float4 v = {wt[0][jj], wt[1][jj], wt[2][jj], wt[3][jj]};
            *(float4*)&V[t4 + jj][r4] = v;
        }
    }
    __syncthreads();
    if (tid < 256) {
        float acc[4][4] = {};
        for (int j = 0; j < 64; ++j) {
            float4 wv = *(const float4*)&V[j][r4];
            float4 xv = *(const float4*)&U[j][t4];
            float ws[4] = {wv.x, wv.y, wv.z, wv.w};
#pragma unroll
            for (int ii = 0; ii < 4; ++ii) {
                acc[ii][0] += ws[ii] * xv.x;
                acc[ii][1] += ws[ii] * xv.y;
                acc[ii][2] += ws[ii] * xv.z;
                acc[ii][3] += ws[ii] * xv.w;
            }
        }
        float Dh = Dp[h];
#pragma unroll
        for (int ii = 0; ii < 4; ++ii) {
            float4 xv = *(const float4*)&U[r4 + ii][t4];
            float4 v = {acc[ii][0] + Dh * xv.x, acc[ii][1] + Dh * xv.y,
                        acc[ii][2] + Dh * xv.z, acc[ii][3] + Dh * xv.w};
            *(float4*)&y[(size_t)(b * L_LEN + l0 + r4 + ii) * DIN_ + h * P_ + t4] = v;
        }
    }
}

// inter-chunk + prefix scan + gating — R11 version (XCD-grouping remap, −10.5us).
__global__ void __launch_bounds__(512) k_inter(const float* __restrict__ Sbuf,
        const float* __restrict__ Ctil, const float* __restrict__ decay,
        const float* __restrict__ zx, const float* __restrict__ y,
        unsigned short* __restrict__ gh, unsigned short* __restrict__ gl,
        float* __restrict__ rowssq) {
    __shared__ float Sm[64][65];
    __shared__ float Cm[64][65];
    const int lin = blockIdx.x + NCH_ * blockIdx.y;   // 0..255
    const int xg = lin & 7, kg = lin >> 3;            // kg 0..31
    const int bh = xg + 8 * (kg >> 4);
    const int c = kg & 15;
    const int b = bh >> 3, h = bh & 7;
    const int l0 = c << 6;
    const int tid = threadIdx.x, wid8 = tid >> 6, lane = tid & 63;
    const size_t bhbase = (size_t)bh * NCH_ * 4096;

    float dec[NCH_];
#pragma unroll
    for (int k = 0; k < NCH_; ++k) dec[k] = decay[bh * NCH_ + k];

    float acc8[8] = {};
    float wgt = 1.f;
    for (int cp = c - 1; cp >= 0; --cp) {
        const float* src = Sbuf + bhbase + (size_t)cp * 4096;
#pragma unroll
        for (int i = 0; i < 8; ++i) acc8[i] += wgt * src[i * 512 + tid];
        wgt *= dec[cp];
    }
#pragma unroll
    for (int i = 0; i < 8; ++i) Sm[i * 8 + wid8][lane] = acc8[i];

    const size_t base = bhbase + (size_t)c * 4096;
    for (int r = 0; r < 64; r += 8) {
        int pp = r + wid8;
        Cm[pp][lane] = Ctil[base + pp * 64 + lane];
    }
    __syncthreads();
    const int t4 = (tid & 15) * 4;
    const int r4 = ((tid >> 4) & 15) * 4;
    if (tid < 256) {
        float acc[4][4] = {};
        if (c > 0) {
            for (int ng = 0; ng < 64; ng += 4) {
                float4 cf[4], sf[4];
#pragma unroll
                for (int ii = 0; ii < 4; ++ii) cf[ii] = *(const float4*)&Cm[r4 + ii][ng];
#pragma unroll
                for (int pp = 0; pp < 4; ++pp) sf[pp] = *(const float4*)&Sm[t4 + pp][ng];
#pragma unroll
                for (int ii = 0; ii < 4; ++ii)
#pragma unroll
                    for (int pp = 0; pp < 4; ++pp)
                        acc[ii][pp] += cf[ii].x * sf[pp].x + cf[ii].y * sf[pp].y +
                                       cf[ii].z * sf[pp].z + cf[ii].w * sf[pp].w;
            }
        }
        float ssq[4];
#pragma unroll
        for (int ii = 0; ii < 4; ++ii) {
            int row = b * L_LEN + l0 + r4 + ii;
            const float* yr = &y[(size_t)row * DIN_ + h * P_ + t4];
            const float* zr = &zx[(size_t)row * DPROJ_ + h * P_ + t4];
            float4 v = *(const float4*)yr;
            float4 z = *(const float4*)zr;
            v.x = (v.x + acc[ii][0]) * siluf(z.x);
            v.y = (v.y + acc[ii][1]) * siluf(z.y);
            v.z = (v.z + acc[ii][2]) * siluf(z.z);
            v.w = (v.w + acc[ii][3]) * siluf(z.w);
            unsigned short h0 = f2bf(v.x), h1 = f2bf(v.y), h2 = f2bf(v.z), h3 = f2bf(v.w);
            us4 hv = {h0, h1, h2, h3};
            us4 lv = {f2bf(v.x - bf2f(h0)), f2bf(v.y - bf2f(h1)),
                      f2bf(v.z - bf2f(h2)), f2bf(v.w - bf2f(h3))};
            *(us4*)&gh[(size_t)row * DIN_ + h * P_ + t4] = hv;
            *(us4*)&gl[(size_t)row * DIN_ + h * P_ + t4] = lv;
            ssq[ii] = v.x * v.x + v.y * v.y + v.z * v.z + v.w * v.w;
        }
#pragma unroll
        for (int o = 1; o < 16; o <<= 1) {
#pragma unroll
            for (int ii = 0; ii < 4; ++ii) ssq[ii] += __shfl_xor(ssq[ii], o, 64);
        }
        if ((tid & 15) == 0) {
#pragma unroll
            for (int ii = 0; ii < 4; ++ii)
                atomicAdd(&rowssq[b * L_LEN + l0 + r4 + ii], ssq[ii]);
        }
    }
}

// pooling partial pass (32 blocks)
__global__ void __launch_bounds__(256) k_pool1(const float* __restrict__ x,
        float* __restrict__ psum, float* __restrict__ pmax) {
    int s = blockIdx.x, b = blockIdx.y, t = threadIdx.x;
    const float* xb = x + ((size_t)b * L_LEN + s * 64) * D_ + t;
    float sm = 0.f, mx = -INFINITY;
    for (int l = 0; l < 64; l += 4) {
        float v0 = xb[(size_t)l * D_];
        float v1 = xb[(size_t)(l + 1) * D_];
        float v2 = xb[(size_t)(l + 2) * D_];
        float v3 = xb[(size_t)(l + 3) * D_];
        sm += v0 + v1 + v2 + v3;
        mx = fmaxf(mx, fmaxf(fmaxf(v0, v1), fmaxf(v2, v3)));
    }
    psum[(b * 16 + s) * 256 + t] = sm;
    pmax[(b * 16 + s) * 256 + t] = mx;
}

// finalize & classifier head (2 blocks x 1024 threads)
__global__ void __launch_bounds__(1024) k_pool2(const float* __restrict__ psum,
                           const float* __restrict__ pmax,
                           const float* __restrict__ pw, const float* __restrict__ pb,
                           const float* __restrict__ c1w, const float* __restrict__ c1b,
                           const float* __restrict__ c2w, const float* __restrict__ c2b,
                           float* __restrict__ out) {
    __shared__ float sp[256], s1[256], s2[128];
    int b = blockIdx.x, tid = threadIdx.x;
    if (tid < 256) {
        float ss = 0.f, mm = -INFINITY;
#pragma unroll
        for (int s = 0; s < 16; ++s) {
            ss += psum[(b * 16 + s) * 256 + tid];
            mm = fmaxf(mm, pmax[(b * 16 + s) * 256 + tid]);
        }
        sp[tid] = (ss * (1.f / L_LEN) + mm) * 0.5f;
    }
    __syncthreads();
    {
        int o = tid >> 2, part = tid & 3;
        const float* wrow = pw + (size_t)o * 256 + part * 64;
        const float* sv = sp + part * 64;
        float acc = 0.f;
        for (int d = 0; d < 64; d += 4) {
            float4 w4 = *(const float4*)(wrow + d);
            float4 x4 = *(const float4*)(sv + d);
            acc += w4.x * x4.x + w4.y * x4.y + w4.z * x4.z + w4.w * x4.w;
        }
        acc += __shfl_xor(acc, 1, 64);
        acc += __shfl_xor(acc, 2, 64);
        if (part == 0) s1[o] = geluf(acc + pb[o]);
    }
    __syncthreads();
    {
        int o = tid >> 3, part = tid & 7;
        const float* wrow = c1w + (size_t)o * 256 + part * 32;
        const float* sv = s1 + part * 32;
        float acc = 0.f;
        for (int d = 0; d < 32; d += 4) {
            float4 w4 = *(const float4*)(wrow + d);
            float4 x4 = *(const float4*)(sv + d);
            acc += w4.x * x4.x + w4.y * x4.y + w4.z * x4.z + w4.w * x4.w;
        }
        acc += __shfl_xor(acc, 1, 64);
        acc += __shfl_xor(acc, 2, 64);
        acc += __shfl_xor(acc, 4, 64);
        if (part == 0) s2[o] = geluf(acc + c1b[o]);
    }
    __syncthreads();
    if (tid < 2) {
        float a = c2b[tid];
        for (int d = 0; d < 128; ++d) a += s2[d] * c2w[tid * 128 + d];
        out[b * NC_ + tid] = a;
    }
}

extern "C" void kernel_launch(void* const* d_in, const int* in_sizes, int n_in,
                              void* d_out, int out_size, void* d_ws, size_t ws_size,
                              hipStream_t stream) {
    const int* ids    = (const int*)d_in[0];
    const float* emb  = (const float*)d_in[1];
    const float* pos  = (const float*)d_in[2];
    const float* Wins = (const float*)d_in[3];
    const float* cw   = (const float*)d_in[4];
    const float* cb   = (const float*)d_in[5];
    const float* dtb  = (const float*)d_in[6];
    const float* Alog = (const float*)d_in[7];
    const float* Dpar = (const float*)d_in[8];
    const float* nw   = (const float*)d_in[9];
    const float* Wout = (const float*)d_in[10];
    const float* pw   = (const float*)d_in[11];
    const float* pb   = (const float*)d_in[12];
    const float* c1w  = (const float*)d_in[13];
    const float* c1b  = (const float*)d_in[14];
    const float* c2w  = (const float*)d_in[15];
    const float* c2b  = (const float*)d_in[16];
    float* out = (float*)d_out;

    const int NWIN = NL_ * DPROJ_ * D_;   // 1187840
    const int NWOUT = NL_ * D_ * DIN_;    // 524288
    const int NG = 1048576;               // 2048*512
    const int NX = 524288;                // 2048*256

    float* ws = (float*)d_ws;
    float* x      = ws;                 // 524288
    float* zx     = x + 524288;         // 2375680
    float* y      = zx + 2375680;       // 1048576
    float* Sbuf   = y + 1048576;        // 1048576
    float* Ctil   = Sbuf + 1048576;     // 1048576
    float* decay  = Ctil + 1048576;     // 256
    float* rowssq = decay + 256;        // 2048
    unsigned short* winh = (unsigned short*)(rowssq + 2048);
    unsigned short* winl = winh + NWIN;
    unsigned short* woh  = winl + NWIN;
    unsigned short* wol  = woh + NWOUT;
    unsigned short* gh   = wol + NWOUT;
    unsigned short* gl   = gh + NG;
    float* psum = (float*)(gl + NG);    // 2*16*256
    float* pmax = psum + 2 * 16 * 256;  // 2*16*256

    const int NPREP = NWIN + NWOUT + NX;
    k_prep<<<(NPREP + 255) / 256, 256, 0, stream>>>(
        Wins, Wout, nw, winh, winl, woh, wol,
        ids, emb, pos, x, NWIN, NWOUT, NX);
    for (int i = 0; i < NL_; ++i) {
        size_t wo_in = (size_t)i * DPROJ_ * D_;
        size_t wo_out = (size_t)i * D_ * DIN_;
        gemm_in<<<dim3(19, 32), 256, 0, stream>>>(
            x, winh + wo_in, winl + wo_in, zx, 2048, DPROJ_, D_);
        k_ssmA<<<dim3(NCH_, 16), 512, 0, stream>>>(
            zx, cw + (size_t)i * CONVDIM_ * 4, cb + (size_t)i * CONVDIM_,
            dtb + i * H_, Alog + i * H_, Dpar + i * H_, Sbuf, decay, Ctil, y, rowssq);
        k_inter<<<dim3(NCH_, 16), 512, 0, stream>>>(Sbuf, Ctil, decay, zx, y, gh, gl, rowssq);
        gemm_outs<<<dim3(4, 32, 4), 256, 0, stream>>>(
            gh, gl, rowssq, woh + wo_out, wol + wo_out, x);
    }
    k_pool1<<<dim3(16, 2), 256, 0, stream>>>(x, psum, pmax);
    k_pool2<<<2, 1024, 0, stream>>>(psum, pmax, pw, pb, c1w, c1b, c2w, c2b, out);
}

// Round 13
// 340.870 us; speedup vs baseline: 1.0031x; 1.0031x over previous
//
#include <hip/hip_runtime.h>
#include <math.h>

#define D_ 256
#define NL_ 4
#define NC_ 2
#define L_LEN 1024
#define NSTATE_ 64
#define DIN_ 512
#define H_ 8
#define P_ 64
#define CONVDIM_ 640
#define DPROJ_ 1160
#define EPS_ 1e-5f
#define NCH_ 16

typedef __attribute__((ext_vector_type(8))) short short8;
typedef __attribute__((ext_vector_type(4))) float f32x4;
typedef __attribute__((ext_vector_type(4))) unsigned short us4;

__device__ __forceinline__ float siluf(float x) { return x / (1.f + __expf(-x)); }
__device__ __forceinline__ float geluf(float x) { return 0.5f * x * (1.f + erff(x * 0.70710678118654752f)); }
__device__ __forceinline__ unsigned short f2bf(float f) {
    unsigned u = __float_as_uint(f);
    u += 0x7FFFu + ((u >> 16) & 1u);
    return (unsigned short)(u >> 16);
}
__device__ __forceinline__ float bf2f(unsigned short h) {
    return __uint_as_float(((unsigned)h) << 16);
}

// merged prep — weight splits + embed in ONE dispatch.
__global__ void k_prep(const float* __restrict__ Wi, const float* __restrict__ Wo,
                       const float* __restrict__ nw,
                       unsigned short* __restrict__ wih, unsigned short* __restrict__ wil,
                       unsigned short* __restrict__ woh, unsigned short* __restrict__ wol,
                       const int* __restrict__ ids, const float* __restrict__ emb,
                       const float* __restrict__ pos, float* __restrict__ x,
                       int nin, int nout, int nemb) {
    int i = blockIdx.x * blockDim.x + threadIdx.x;
    if (i < nin) {
        float f = Wi[i];
        unsigned short h = f2bf(f);
        wih[i] = h;
        wil[i] = f2bf(f - bf2f(h));
    } else if (i < nin + nout) {
        int j = i - nin;
        int layer = j / (D_ * DIN_);
        int k = j % DIN_;
        float f = Wo[j] * nw[layer * DIN_ + k];
        unsigned short h = f2bf(f);
        woh[j] = h;
        wol[j] = f2bf(f - bf2f(h));
    } else if (i < nin + nout + nemb) {
        int k = i - nin - nout;
        int d = k & (D_ - 1);
        int bl = k >> 8;
        int l = bl & (L_LEN - 1);
        x[k] = emb[ids[bl] * D_ + d] + pos[l * D_ + d];
    }
}

// in-proj: zx[M,N] = x[M,K] @ Win^T.  A = f32 inline hi/lo split; B pre-split.
// R26 (=untested R23 lever): BN=32 -> grid (37, 32) = 1184 blocks, ~4.6
// waves/SIMD (was 2.4). Same k-slice order -> bit-identical. LDS 27.7KB.
__global__ void __launch_bounds__(256) gemm_in(const float* __restrict__ A,
        const unsigned short* __restrict__ Bhi, const unsigned short* __restrict__ Blo,
        float* __restrict__ C, int M, int N, int K) {
    __shared__ __align__(16) unsigned short Ah[64 * 72];
    __shared__ __align__(16) unsigned short Al[64 * 72];
    __shared__ __align__(16) unsigned short Bh[32 * 72];
    __shared__ __align__(16) unsigned short Bl[32 * 72];
    const int tid = threadIdx.x;
    const int col0 = blockIdx.x * 32;
    const int row0 = blockIdx.y * 64;

    const int sar = tid >> 2, sas = (tid & 3) * 16;   // A: 64 rows x 4 thr x 16 elems
    const int sbr = tid >> 3, sbs = (tid & 7) * 8;    // B: 32 rows x 8 thr x 8 shorts
    const bool bok = (col0 + sbr) < N;
    const float* aptr = A + (size_t)(row0 + sar) * K + sas;
    const unsigned short* bhptr = Bhi + (size_t)(col0 + sbr) * K + sbs;
    const unsigned short* blptr = Blo + (size_t)(col0 + sbr) * K + sbs;

    float4 pa[4];
#pragma unroll
    for (int i = 0; i < 4; ++i) pa[i] = *(const float4*)(aptr + i * 4);
    short8 pbh = {0,0,0,0,0,0,0,0}, pbl = {0,0,0,0,0,0,0,0};
    if (bok) {
        pbh = *(const short8*)bhptr;
        pbl = *(const short8*)blptr;
    }

    const int wave = tid >> 6, lane = tid & 63;
    const int lq = lane >> 4, lm = lane & 15;
    f32x4 acc[2] = {};
    const int nsteps = K >> 6;   // BK=64
    for (int s = 0; s < nsteps; ++s) {
        __syncthreads();
#pragma unroll
        for (int i = 0; i < 4; ++i) {
            float4 f = pa[i];
            unsigned short h0 = f2bf(f.x), h1 = f2bf(f.y), h2 = f2bf(f.z), h3 = f2bf(f.w);
            us4 hv = {h0, h1, h2, h3};
            us4 lv = {f2bf(f.x - bf2f(h0)), f2bf(f.y - bf2f(h1)),
                      f2bf(f.z - bf2f(h2)), f2bf(f.w - bf2f(h3))};
            *(us4*)&Ah[sar * 72 + sas + i * 4] = hv;
            *(us4*)&Al[sar * 72 + sas + i * 4] = lv;
        }
        *(short8*)&Bh[sbr * 72 + sbs] = pbh;
        *(short8*)&Bl[sbr * 72 + sbs] = pbl;
        __syncthreads();
        if (s + 1 < nsteps) {
            int ko = (s + 1) * 64;
#pragma unroll
            for (int i = 0; i < 4; ++i) pa[i] = *(const float4*)(aptr + ko + i * 4);
            if (bok) {
                pbh = *(const short8*)(bhptr + ko);
                pbl = *(const short8*)(blptr + ko);
            }
        }
#pragma unroll
        for (int k32 = 0; k32 < 2; ++k32) {
            const int kof = k32 * 32 + lq * 8;
            short8 bh[2], bl[2];
#pragma unroll
            for (int ct = 0; ct < 2; ++ct) {
                bh[ct] = *(const short8*)&Bh[(ct * 16 + lm) * 72 + kof];
                bl[ct] = *(const short8*)&Bl[(ct * 16 + lm) * 72 + kof];
            }
            short8 ah = *(const short8*)&Ah[(wave * 16 + lm) * 72 + kof];
            short8 al = *(const short8*)&Al[(wave * 16 + lm) * 72 + kof];
#pragma unroll
            for (int ct = 0; ct < 2; ++ct) {
                acc[ct] = __builtin_amdgcn_mfma_f32_16x16x32_bf16(ah, bh[ct], acc[ct], 0, 0, 0);
                acc[ct] = __builtin_amdgcn_mfma_f32_16x16x32_bf16(ah, bl[ct], acc[ct], 0, 0, 0);
                acc[ct] = __builtin_amdgcn_mfma_f32_16x16x32_bf16(al, bh[ct], acc[ct], 0, 0, 0);
            }
        }
    }
#pragma unroll
    for (int ct = 0; ct < 2; ++ct) {
        int col = col0 + ct * 16 + lm;
        if (col >= N) continue;
        int rbase = row0 + wave * 16 + lq * 4;
#pragma unroll
        for (int reg = 0; reg < 4; ++reg) {
            C[(size_t)(rbase + reg) * N + col] = acc[ct][reg];
        }
    }
}

// out-proj: x[m][n] += sc[m]*sum_k g[m][k]*(W*nw)[n][k]; split-K 4, BK=64.
// EXACT R7/R4/R11 version (R12's XCD remap was neutral-negative; reverted).
__global__ void __launch_bounds__(256) gemm_outs(const unsigned short* __restrict__ Ghg,
        const unsigned short* __restrict__ Glg, const float* __restrict__ rowssq,
        const unsigned short* __restrict__ Bhi, const unsigned short* __restrict__ Blo,
        float* __restrict__ x) {
    __shared__ __align__(16) unsigned short Ah[64 * 72];
    __shared__ __align__(16) unsigned short Al[64 * 72];
    __shared__ __align__(16) unsigned short Bh[64 * 72];
    __shared__ __align__(16) unsigned short Bl[64 * 72];
    const int tid = threadIdx.x;
    const int col0 = blockIdx.x * 64;
    const int row0 = blockIdx.y * 64;
    const int kbase = blockIdx.z * 128;
    const int sar = tid >> 2, sas = (tid & 3) * 16;
    const unsigned short* ahptr = Ghg + (size_t)(row0 + sar) * DIN_ + kbase + sas;
    const unsigned short* alptr = Glg + (size_t)(row0 + sar) * DIN_ + kbase + sas;
    const unsigned short* bhptr = Bhi + (size_t)(col0 + sar) * DIN_ + kbase + sas;
    const unsigned short* blptr = Blo + (size_t)(col0 + sar) * DIN_ + kbase + sas;

    short8 pah0 = *(const short8*)ahptr, pah1 = *(const short8*)(ahptr + 8);
    short8 pal0 = *(const short8*)alptr, pal1 = *(const short8*)(alptr + 8);
    short8 pbh0 = *(const short8*)bhptr, pbh1 = *(const short8*)(bhptr + 8);
    short8 pbl0 = *(const short8*)blptr, pbl1 = *(const short8*)(blptr + 8);

    const int wave = tid >> 6, lane = tid & 63;
    const int lq = lane >> 4, lm = lane & 15;
    f32x4 acc[4] = {};
    for (int s = 0; s < 2; ++s) {
        __syncthreads();
        *(short8*)&Ah[sar * 72 + sas] = pah0;
        *(short8*)&Ah[sar * 72 + sas + 8] = pah1;
        *(short8*)&Al[sar * 72 + sas] = pal0;
        *(short8*)&Al[sar * 72 + sas + 8] = pal1;
        *(short8*)&Bh[sar * 72 + sas] = pbh0;
        *(short8*)&Bh[sar * 72 + sas + 8] = pbh1;
        *(short8*)&Bl[sar * 72 + sas] = pbl0;
        *(short8*)&Bl[sar * 72 + sas + 8] = pbl1;
        __syncthreads();
        if (s + 1 < 2) {
            int ko = 64;
            pah0 = *(const short8*)(ahptr + ko); pah1 = *(const short8*)(ahptr + ko + 8);
            pal0 = *(const short8*)(alptr + ko); pal1 = *(const short8*)(alptr + ko + 8);
            pbh0 = *(const short8*)(bhptr + ko); pbh1 = *(const short8*)(bhptr + ko + 8);
            pbl0 = *(const short8*)(blptr + ko); pbl1 = *(const short8*)(blptr + ko + 8);
        }
#pragma unroll
        for (int k32 = 0; k32 < 2; ++k32) {
            const int kof = k32 * 32 + lq * 8;
            short8 bh[4], bl[4];
#pragma unroll
            for (int ct = 0; ct < 4; ++ct) {
                bh[ct] = *(const short8*)&Bh[(ct * 16 + lm) * 72 + kof];
                bl[ct] = *(const short8*)&Bl[(ct * 16 + lm) * 72 + kof];
            }
            short8 ah = *(const short8*)&Ah[(wave * 16 + lm) * 72 + kof];
            short8 al = *(const short8*)&Al[(wave * 16 + lm) * 72 + kof];
#pragma unroll
            for (int ct = 0; ct < 4; ++ct) {
                acc[ct] = __builtin_amdgcn_mfma_f32_16x16x32_bf16(ah, bh[ct], acc[ct], 0, 0, 0);
                acc[ct] = __builtin_amdgcn_mfma_f32_16x16x32_bf16(ah, bl[ct], acc[ct], 0, 0, 0);
                acc[ct] = __builtin_amdgcn_mfma_f32_16x16x32_bf16(al, bh[ct], acc[ct], 0, 0, 0);
            }
        }
    }
    {
        int rbase = row0 + wave * 16 + lq * 4;
        float sc[4];
#pragma unroll
        for (int reg = 0; reg < 4; ++reg)
            sc[reg] = rsqrtf(rowssq[rbase + reg] * (1.f / DIN_) + EPS_);
#pragma unroll
        for (int ct = 0; ct < 4; ++ct) {
            int col = col0 + ct * 16 + lm;
#pragma unroll
            for (int reg = 0; reg < 4; ++reg) {
                atomicAdd(&x[(size_t)(rbase + reg) * D_ + col], sc[reg] * acc[ct][reg]);
            }
        }
    }
}

// Fused SSM part A — EXACT R4 version (frozen).
__global__ void __launch_bounds__(512) k_ssmA(const float* __restrict__ zx,
        const float* __restrict__ cw, const float* __restrict__ cb,
        const float* __restrict__ dtbias, const float* __restrict__ Alog,
        const float* __restrict__ Dp,
        float* __restrict__ Sbuf, float* __restrict__ decay,
        float* __restrict__ Ctil, float* __restrict__ y, float* __restrict__ rowssq) {
    __shared__ float U[64][65];
    __shared__ float V[64][65];
    __shared__ float W[64][65];
    __shared__ float sdt[64], cs[64], wj[64];
    const int c = blockIdx.x, bh = blockIdx.y;
    const int b = bh >> 3, h = bh & 7;
    const int l0 = c << 6;
    const int tid = threadIdx.x, wid8 = tid >> 6, lane = tid & 63;

    if (h == 0 && tid < 64) rowssq[b * L_LEN + l0 + tid] = 0.f;

    const int chx = h * P_ + lane;
    const int chb = DIN_ + lane;
    const int chc = DIN_ + NSTATE_ + lane;
    float wx0 = cw[chx * 4], wx1 = cw[chx * 4 + 1], wx2 = cw[chx * 4 + 2], wx3 = cw[chx * 4 + 3];
    float wb0 = cw[chb * 4], wb1 = cw[chb * 4 + 1], wb2 = cw[chb * 4 + 2], wb3 = cw[chb * 4 + 3];
    float wc0 = cw[chc * 4], wc1 = cw[chc * 4 + 1], wc2 = cw[chc * 4 + 2], wc3 = cw[chc * 4 + 3];
    float bx = cb[chx], bb = cb[chb], bc = cb[chc];

    for (int r = 0; r < 64; r += 8) {
        int j = r + wid8;
        int l = l0 + j;
        float ax = bx, ab = bb, ac = bc;
#pragma unroll
        for (int k = 0; k < 4; ++k) {
            int t = l - 3 + k;
            if (t >= 0) {
                const float* row = zx + (size_t)(b * L_LEN + t) * DPROJ_;
                float wxk = (k == 0) ? wx0 : (k == 1) ? wx1 : (k == 2) ? wx2 : wx3;
                float wbk = (k == 0) ? wb0 : (k == 1) ? wb1 : (k == 2) ? wb2 : wb3;
                float wck = (k == 0) ? wc0 : (k == 1) ? wc1 : (k == 2) ? wc2 : wc3;
                ax += wxk * row[DIN_ + chx];
                ab += wbk * row[DIN_ + chb];
                ac += wck * row[DIN_ + chc];
            }
        }
        U[j][lane] = siluf(ax);
        V[j][lane] = siluf(ab);
        W[j][lane] = siluf(ac);
    }
    if (tid < 64) {
        float xv = zx[(size_t)(b * L_LEN + l0 + tid) * DPROJ_ + (DPROJ_ - H_) + h] + dtbias[h];
        float sp = fmaxf(xv, 0.f) + log1pf(__expf(-fabsf(xv)));
        sdt[tid] = sp;
        float v = sp * (-__expf(Alog[h]));
#pragma unroll
        for (int off = 1; off < 64; off <<= 1) {
            float t = __shfl_up(v, off, 64);
            if (tid >= off) v += t;
        }
        cs[tid] = v;
        float tot = __shfl(v, 63, 64);
        wj[tid] = __expf(tot - v) * sp;
        if (tid == 63) decay[bh * NCH_ + c] = __expf(tot);
    }
    __syncthreads();

    const int t4 = (tid & 15) * 4;
    const int r4 = ((tid >> 4) & 15) * 4;
    const size_t sbase = (size_t)(bh * NCH_ + c) * 4096;

    if (tid < 256) {
        float acc[4][4] = {};
        for (int j = 0; j < 64; ++j) {
            float w = wj[j];
            float4 xv = *(const float4*)&U[j][r4];
            float4 bv = *(const float4*)&V[j][t4];
            float xw[4] = {xv.x * w, xv.y * w, xv.z * w, xv.w * w};
#pragma unroll
            for (int ii = 0; ii < 4; ++ii) {
                acc[ii][0] += xw[ii] * bv.x;
                acc[ii][1] += xw[ii] * bv.y;
                acc[ii][2] += xw[ii] * bv.z;
                acc[ii][3] += xw[ii] * bv.w;
            }
        }
#pragma unroll
        for (int ii = 0; ii < 4; ++ii) {
            float4 v = {acc[ii][0], acc[ii][1], acc[ii][2], acc[ii][3]};
            *(float4*)&Sbuf[sbase + (size_t)(r4 + ii) * 64 + t4] = v;
        }
    }
    for (int r = 0; r < 64; r += 8) {
        int ii = r + wid8;
        Ctil[sbase + ii * 64 + lane] = __expf(cs[ii]) * W[ii][lane];
    }
    float wt[4][4];
    if (tid < 256) {
        float g[4][4] = {};
        for (int ng = 0; ng < 64; ng += 4) {
            float4 cf[4], bf[4];
#pragma unroll
            for (int ii = 0; ii < 4; ++ii) cf[ii] = *(const float4*)&W[r4 + ii][ng];
#pragma unroll
            for (int jj = 0; jj < 4; ++jj) bf[jj] = *(const float4*)&V[t4 + jj][ng];
#pragma unroll
            for (int ii = 0; ii < 4; ++ii)
#pragma unroll
                for (int jj = 0; jj < 4; ++jj)
                    g[ii][jj] += cf[ii].x * bf[jj].x + cf[ii].y * bf[jj].y +
                                 cf[ii].z * bf[jj].z + cf[ii].w * bf[jj].w;
        }
#pragma unroll
        for (int ii = 0; ii < 4; ++ii) {
            int i = r4 + ii;
            float csi = cs[i];
#pragma unroll
            for (int jj = 0; jj < 4; ++jj) {
                int j = t4 + jj;
                wt[ii][jj] = (j <= i) ? __expf(fminf(csi - cs[j], 0.f)) * sdt[j] * g[ii][jj] : 0.f;
            }
        }
    }
    __syncthreads();
    if (tid < 256) {
#pragma unroll
        for (int jj = 0; jj < 4; ++jj) {
            float4 v = {wt[0][jj], wt[1][jj], wt[2][jj], wt[3][jj]};
            *(float4*)&V[t4 + jj][r4] = v;
        }
    }
    __syncthreads();
    if (tid < 256) {
        float acc[4][4] = {};
        for (int j = 0; j < 64; ++j) {
            float4 wv = *(const float4*)&V[j][r4];
            float4 xv = *(const float4*)&U[j][t4];
            float ws[4] = {wv.x, wv.y, wv.z, wv.w};
#pragma unroll
            for (int ii = 0; ii < 4; ++ii) {
                acc[ii][0] += ws[ii] * xv.x;
                acc[ii][1] += ws[ii] * xv.y;
                acc[ii][2] += ws[ii] * xv.z;
                acc[ii][3] += ws[ii] * xv.w;
            }
        }
        float Dh = Dp[h];
#pragma unroll
        for (int ii = 0; ii < 4; ++ii) {
            float4 xv = *(const float4*)&U[r4 + ii][t4];
            float4 v = {acc[ii][0] + Dh * xv.x, acc[ii][1] + Dh * xv.y,
                        acc[ii][2] + Dh * xv.z, acc[ii][3] + Dh * xv.w};
            *(float4*)&y[(size_t)(b * L_LEN + l0 + r4 + ii) * DIN_ + h * P_ + t4] = v;
        }
    }
}

// inter-chunk + prefix scan + gating — R11 version (XCD-grouping remap, −10.5us).
__global__ void __launch_bounds__(512) k_inter(const float* __restrict__ Sbuf,
        const float* __restrict__ Ctil, const float* __restrict__ decay,
        const float* __restrict__ zx, const float* __restrict__ y,
        unsigned short* __restrict__ gh, unsigned short* __restrict__ gl,
        float* __restrict__ rowssq) {
    __shared__ float Sm[64][65];
    __shared__ float Cm[64][65];
    const int lin = blockIdx.x + NCH_ * blockIdx.y;   // 0..255
    const int xg = lin & 7, kg = lin >> 3;            // kg 0..31
    const int bh = xg + 8 * (kg >> 4);
    const int c = kg & 15;
    const int b = bh >> 3, h = bh & 7;
    const int l0 = c << 6;
    const int tid = threadIdx.x, wid8 = tid >> 6, lane = tid & 63;
    const size_t bhbase = (size_t)bh * NCH_ * 4096;

    float dec[NCH_];
#pragma unroll
    for (int k = 0; k < NCH_; ++k) dec[k] = decay[bh * NCH_ + k];

    float acc8[8] = {};
    float wgt = 1.f;
    for (int cp = c - 1; cp >= 0; --cp) {
        const float* src = Sbuf + bhbase + (size_t)cp * 4096;
#pragma unroll
        for (int i = 0; i < 8; ++i) acc8[i] += wgt * src[i * 512 + tid];
        wgt *= dec[cp];
    }
#pragma unroll
    for (int i = 0; i < 8; ++i) Sm[i * 8 + wid8][lane] = acc8[i];

    const size_t base = bhbase + (size_t)c * 4096;
    for (int r = 0; r < 64; r += 8) {
        int pp = r + wid8;
        Cm[pp][lane] = Ctil[base + pp * 64 + lane];
    }
    __syncthreads();
    const int t4 = (tid & 15) * 4;
    const int r4 = ((tid >> 4) & 15) * 4;
    if (tid < 256) {
        float acc[4][4] = {};
        if (c > 0) {
            for (int ng = 0; ng < 64; ng += 4) {
                float4 cf[4], sf[4];
#pragma unroll
                for (int ii = 0; ii < 4; ++ii) cf[ii] = *(const float4*)&Cm[r4 + ii][ng];
#pragma unroll
                for (int pp = 0; pp < 4; ++pp) sf[pp] = *(const float4*)&Sm[t4 + pp][ng];
#pragma unroll
                for (int ii = 0; ii < 4; ++ii)
#pragma unroll
                    for (int pp = 0; pp < 4; ++pp)
                        acc[ii][pp] += cf[ii].x * sf[pp].x + cf[ii].y * sf[pp].y +
                                       cf[ii].z * sf[pp].z + cf[ii].w * sf[pp].w;
            }
        }
        float ssq[4];
#pragma unroll
        for (int ii = 0; ii < 4; ++ii) {
            int row = b * L_LEN + l0 + r4 + ii;
            const float* yr = &y[(size_t)row * DIN_ + h * P_ + t4];
            const float* zr = &zx[(size_t)row * DPROJ_ + h * P_ + t4];
            float4 v = *(const float4*)yr;
            float4 z = *(const float4*)zr;
            v.x = (v.x + acc[ii][0]) * siluf(z.x);
            v.y = (v.y + acc[ii][1]) * siluf(z.y);
            v.z = (v.z + acc[ii][2]) * siluf(z.z);
            v.w = (v.w + acc[ii][3]) * siluf(z.w);
            unsigned short h0 = f2bf(v.x), h1 = f2bf(v.y), h2 = f2bf(v.z), h3 = f2bf(v.w);
            us4 hv = {h0, h1, h2, h3};
            us4 lv = {f2bf(v.x - bf2f(h0)), f2bf(v.y - bf2f(h1)),
                      f2bf(v.z - bf2f(h2)), f2bf(v.w - bf2f(h3))};
            *(us4*)&gh[(size_t)row * DIN_ + h * P_ + t4] = hv;
            *(us4*)&gl[(size_t)row * DIN_ + h * P_ + t4] = lv;
            ssq[ii] = v.x * v.x + v.y * v.y + v.z * v.z + v.w * v.w;
        }
#pragma unroll
        for (int o = 1; o < 16; o <<= 1) {
#pragma unroll
            for (int ii = 0; ii < 4; ++ii) ssq[ii] += __shfl_xor(ssq[ii], o, 64);
        }
        if ((tid & 15) == 0) {
#pragma unroll
            for (int ii = 0; ii < 4; ++ii)
                atomicAdd(&rowssq[b * L_LEN + l0 + r4 + ii], ssq[ii]);
        }
    }
}

// pooling partial pass (32 blocks)
__global__ void __launch_bounds__(256) k_pool1(const float* __restrict__ x,
        float* __restrict__ psum, float* __restrict__ pmax) {
    int s = blockIdx.x, b = blockIdx.y, t = threadIdx.x;
    const float* xb = x + ((size_t)b * L_LEN + s * 64) * D_ + t;
    float sm = 0.f, mx = -INFINITY;
    for (int l = 0; l < 64; l += 4) {
        float v0 = xb[(size_t)l * D_];
        float v1 = xb[(size_t)(l + 1) * D_];
        float v2 = xb[(size_t)(l + 2) * D_];
        float v3 = xb[(size_t)(l + 3) * D_];
        sm += v0 + v1 + v2 + v3;
        mx = fmaxf(mx, fmaxf(fmaxf(v0, v1), fmaxf(v2, v3)));
    }
    psum[(b * 16 + s) * 256 + t] = sm;
    pmax[(b * 16 + s) * 256 + t] = mx;
}

// finalize & classifier head (2 blocks x 1024 threads)
__global__ void __launch_bounds__(1024) k_pool2(const float* __restrict__ psum,
                           const float* __restrict__ pmax,
                           const float* __restrict__ pw, const float* __restrict__ pb,
                           const float* __restrict__ c1w, const float* __restrict__ c1b,
                           const float* __restrict__ c2w, const float* __restrict__ c2b,
                           float* __restrict__ out) {
    __shared__ float sp[256], s1[256], s2[128];
    int b = blockIdx.x, tid = threadIdx.x;
    if (tid < 256) {
        float ss = 0.f, mm = -INFINITY;
#pragma unroll
        for (int s = 0; s < 16; ++s) {
            ss += psum[(b * 16 + s) * 256 + tid];
            mm = fmaxf(mm, pmax[(b * 16 + s) * 256 + tid]);
        }
        sp[tid] = (ss * (1.f / L_LEN) + mm) * 0.5f;
    }
    __syncthreads();
    {
        int o = tid >> 2, part = tid & 3;
        const float* wrow = pw + (size_t)o * 256 + part * 64;
        const float* sv = sp + part * 64;
        float acc = 0.f;
        for (int d = 0; d < 64; d += 4) {
            float4 w4 = *(const float4*)(wrow + d);
            float4 x4 = *(const float4*)(sv + d);
            acc += w4.x * x4.x + w4.y * x4.y + w4.z * x4.z + w4.w * x4.w;
        }
        acc += __shfl_xor(acc, 1, 64);
        acc += __shfl_xor(acc, 2, 64);
        if (part == 0) s1[o] = geluf(acc + pb[o]);
    }
    __syncthreads();
    {
        int o = tid >> 3, part = tid & 7;
        const float* wrow = c1w + (size_t)o * 256 + part * 32;
        const float* sv = s1 + part * 32;
        float acc = 0.f;
        for (int d = 0; d < 32; d += 4) {
            float4 w4 = *(const float4*)(wrow + d);
            float4 x4 = *(const float4*)(sv + d);
            acc += w4.x * x4.x + w4.y * x4.y + w4.z * x4.z + w4.w * x4.w;
        }
        acc += __shfl_xor(acc, 1, 64);
        acc += __shfl_xor(acc, 2, 64);
        acc += __shfl_xor(acc, 4, 64);
        if (part == 0) s2[o] = geluf(acc + c1b[o]);
    }
    __syncthreads();
    if (tid < 2) {
        float a = c2b[tid];
        for (int d = 0; d < 128; ++d) a += s2[d] * c2w[tid * 128 + d];
        out[b * NC_ + tid] = a;
    }
}

extern "C" void kernel_launch(void* const* d_in, const int* in_sizes, int n_in,
                              void* d_out, int out_size, void* d_ws, size_t ws_size,
                              hipStream_t stream) {
    const int* ids    = (const int*)d_in[0];
    const float* emb  = (const float*)d_in[1];
    const float* pos  = (const float*)d_in[2];
    const float* Wins = (const float*)d_in[3];
    const float* cw   = (const float*)d_in[4];
    const float* cb   = (const float*)d_in[5];
    const float* dtb  = (const float*)d_in[6];
    const float* Alog = (const float*)d_in[7];
    const float* Dpar = (const float*)d_in[8];
    const float* nw   = (const float*)d_in[9];
    const float* Wout = (const float*)d_in[10];
    const float* pw   = (const float*)d_in[11];
    const float* pb   = (const float*)d_in[12];
    const float* c1w  = (const float*)d_in[13];
    const float* c1b  = (const float*)d_in[14];
    const float* c2w  = (const float*)d_in[15];
    const float* c2b  = (const float*)d_in[16];
    float* out = (float*)d_out;

    const int NWIN = NL_ * DPROJ_ * D_;   // 1187840
    const int NWOUT = NL_ * D_ * DIN_;    // 524288
    const int NG = 1048576;               // 2048*512
    const int NX = 524288;                // 2048*256

    float* ws = (float*)d_ws;
    float* x      = ws;                 // 524288
    float* zx     = x + 524288;         // 2375680
    float* y      = zx + 2375680;       // 1048576
    float* Sbuf   = y + 1048576;        // 1048576
    float* Ctil   = Sbuf + 1048576;     // 1048576
    float* decay  = Ctil + 1048576;     // 256
    float* rowssq = decay + 256;        // 2048
    unsigned short* winh = (unsigned short*)(rowssq + 2048);
    unsigned short* winl = winh + NWIN;
    unsigned short* woh  = winl + NWIN;
    unsigned short* wol  = woh + NWOUT;
    unsigned short* gh   = wol + NWOUT;
    unsigned short* gl   = gh + NG;
    float* psum = (float*)(gl + NG);    // 2*16*256
    float* pmax = psum + 2 * 16 * 256;  // 2*16*256

    const int NPREP = NWIN + NWOUT + NX;
    k_prep<<<(NPREP + 255) / 256, 256, 0, stream>>>(
        Wins, Wout, nw, winh, winl, woh, wol,
        ids, emb, pos, x, NWIN, NWOUT, NX);
    for (int i = 0; i < NL_; ++i) {
        size_t wo_in = (size_t)i * DPROJ_ * D_;
        size_t wo_out = (size_t)i * D_ * DIN_;
        gemm_in<<<dim3(37, 32), 256, 0, stream>>>(
            x, winh + wo_in, winl + wo_in, zx, 2048, DPROJ_, D_);
        k_ssmA<<<dim3(NCH_, 16), 512, 0, stream>>>(
            zx, cw + (size_t)i * CONVDIM_ * 4, cb + (size_t)i * CONVDIM_,
            dtb + i * H_, Alog + i * H_, Dpar + i * H_, Sbuf, decay, Ctil, y, rowssq);
        k_inter<<<dim3(NCH_, 16), 512, 0, stream>>>(Sbuf, Ctil, decay, zx, y, gh, gl, rowssq);
        gemm_outs<<<dim3(4, 32, 4), 256, 0, stream>>>(
            gh, gl, rowssq, woh + wo_out, wol + wo_out, x);
    }
    k_pool1<<<dim3(16, 2), 256, 0, stream>>>(x, psum, pmax);
    k_pool2<<<2, 1024, 0, stream>>>(psum, pmax, pw, pb, c1w, c1b, c2w, c2b, out);
}

// Round 14
// 335.676 us; speedup vs baseline: 1.0186x; 1.0155x over previous
//
#include <hip/hip_runtime.h>
#include <math.h>

#define D_ 256
#define NL_ 4
#define NC_ 2
#define L_LEN 1024
#define NSTATE_ 64
#define DIN_ 512
#define H_ 8
#define P_ 64
#define CONVDIM_ 640
#define DPROJ_ 1160
#define EPS_ 1e-5f
#define NCH_ 16

typedef __attribute__((ext_vector_type(8))) short short8;
typedef __attribute__((ext_vector_type(4))) float f32x4;
typedef __attribute__((ext_vector_type(4))) unsigned short us4;

__device__ __forceinline__ float siluf(float x) { return x / (1.f + __expf(-x)); }
__device__ __forceinline__ float geluf(float x) { return 0.5f * x * (1.f + erff(x * 0.70710678118654752f)); }
__device__ __forceinline__ unsigned short f2bf(float f) {
    unsigned u = __float_as_uint(f);
    u += 0x7FFFu + ((u >> 16) & 1u);
    return (unsigned short)(u >> 16);
}
__device__ __forceinline__ float bf2f(unsigned short h) {
    return __uint_as_float(((unsigned)h) << 16);
}

// merged prep — weight splits + embed in ONE dispatch.
__global__ void k_prep(const float* __restrict__ Wi, const float* __restrict__ Wo,
                       const float* __restrict__ nw,
                       unsigned short* __restrict__ wih, unsigned short* __restrict__ wil,
                       unsigned short* __restrict__ woh, unsigned short* __restrict__ wol,
                       const int* __restrict__ ids, const float* __restrict__ emb,
                       const float* __restrict__ pos, float* __restrict__ x,
                       int nin, int nout, int nemb) {
    int i = blockIdx.x * blockDim.x + threadIdx.x;
    if (i < nin) {
        float f = Wi[i];
        unsigned short h = f2bf(f);
        wih[i] = h;
        wil[i] = f2bf(f - bf2f(h));
    } else if (i < nin + nout) {
        int j = i - nin;
        int layer = j / (D_ * DIN_);
        int k = j % DIN_;
        float f = Wo[j] * nw[layer * DIN_ + k];
        unsigned short h = f2bf(f);
        woh[j] = h;
        wol[j] = f2bf(f - bf2f(h));
    } else if (i < nin + nout + nemb) {
        int k = i - nin - nout;
        int d = k & (D_ - 1);
        int bl = k >> 8;
        int l = bl & (L_LEN - 1);
        x[k] = emb[ids[bl] * D_ + d] + pos[l * D_ + d];
    }
}

// in-proj: zx[M,N] = x[M,K] @ Win^T.  EXACT R7/R11 version (best: 336.5us):
// A = f32 inline hi/lo split, B pre-split bf16, BK=64, BM=64, BN=64,
// grid (19, 32), single-buffered, natural block map.
// (R13's BN=32 was +4.4us: A-panel staging traffic doubles, cancels occupancy.)
__global__ void __launch_bounds__(256) gemm_in(const float* __restrict__ A,
        const unsigned short* __restrict__ Bhi, const unsigned short* __restrict__ Blo,
        float* __restrict__ C, int M, int N, int K) {
    __shared__ __align__(16) unsigned short Ah[64 * 72];
    __shared__ __align__(16) unsigned short Al[64 * 72];
    __shared__ __align__(16) unsigned short Bh[64 * 72];
    __shared__ __align__(16) unsigned short Bl[64 * 72];
    const int tid = threadIdx.x;
    const int col0 = blockIdx.x * 64;
    const int row0 = blockIdx.y * 64;

    const int sar = tid >> 2, sas = (tid & 3) * 16;   // 64 rows x 4 thr x 16 elems
    const bool bok = (col0 + sar) < N;
    const float* aptr = A + (size_t)(row0 + sar) * K + sas;
    const unsigned short* bhptr = Bhi + (size_t)(col0 + sar) * K + sas;
    const unsigned short* blptr = Blo + (size_t)(col0 + sar) * K + sas;

    float4 pa[4];
#pragma unroll
    for (int i = 0; i < 4; ++i) pa[i] = *(const float4*)(aptr + i * 4);
    short8 pbh0 = {0,0,0,0,0,0,0,0}, pbh1 = {0,0,0,0,0,0,0,0};
    short8 pbl0 = {0,0,0,0,0,0,0,0}, pbl1 = {0,0,0,0,0,0,0,0};
    if (bok) {
        pbh0 = *(const short8*)bhptr; pbh1 = *(const short8*)(bhptr + 8);
        pbl0 = *(const short8*)blptr; pbl1 = *(const short8*)(blptr + 8);
    }

    const int wave = tid >> 6, lane = tid & 63;
    const int lq = lane >> 4, lm = lane & 15;
    f32x4 acc[4] = {};
    const int nsteps = K >> 6;   // BK=64
    for (int s = 0; s < nsteps; ++s) {
        __syncthreads();
#pragma unroll
        for (int i = 0; i < 4; ++i) {
            float4 f = pa[i];
            unsigned short h0 = f2bf(f.x), h1 = f2bf(f.y), h2 = f2bf(f.z), h3 = f2bf(f.w);
            us4 hv = {h0, h1, h2, h3};
            us4 lv = {f2bf(f.x - bf2f(h0)), f2bf(f.y - bf2f(h1)),
                      f2bf(f.z - bf2f(h2)), f2bf(f.w - bf2f(h3))};
            *(us4*)&Ah[sar * 72 + sas + i * 4] = hv;
            *(us4*)&Al[sar * 72 + sas + i * 4] = lv;
        }
        *(short8*)&Bh[sar * 72 + sas] = pbh0;
        *(short8*)&Bh[sar * 72 + sas + 8] = pbh1;
        *(short8*)&Bl[sar * 72 + sas] = pbl0;
        *(short8*)&Bl[sar * 72 + sas + 8] = pbl1;
        __syncthreads();
        if (s + 1 < nsteps) {
            int ko = (s + 1) * 64;
#pragma unroll
            for (int i = 0; i < 4; ++i) pa[i] = *(const float4*)(aptr + ko + i * 4);
            if (bok) {
                pbh0 = *(const short8*)(bhptr + ko); pbh1 = *(const short8*)(bhptr + ko + 8);
                pbl0 = *(const short8*)(blptr + ko); pbl1 = *(const short8*)(blptr + ko + 8);
            }
        }
#pragma unroll
        for (int k32 = 0; k32 < 2; ++k32) {
            const int kof = k32 * 32 + lq * 8;
            short8 bh[4], bl[4];
#pragma unroll
            for (int ct = 0; ct < 4; ++ct) {
                bh[ct] = *(const short8*)&Bh[(ct * 16 + lm) * 72 + kof];
                bl[ct] = *(const short8*)&Bl[(ct * 16 + lm) * 72 + kof];
            }
            short8 ah = *(const short8*)&Ah[(wave * 16 + lm) * 72 + kof];
            short8 al = *(const short8*)&Al[(wave * 16 + lm) * 72 + kof];
#pragma unroll
            for (int ct = 0; ct < 4; ++ct) {
                acc[ct] = __builtin_amdgcn_mfma_f32_16x16x32_bf16(ah, bh[ct], acc[ct], 0, 0, 0);
                acc[ct] = __builtin_amdgcn_mfma_f32_16x16x32_bf16(ah, bl[ct], acc[ct], 0, 0, 0);
                acc[ct] = __builtin_amdgcn_mfma_f32_16x16x32_bf16(al, bh[ct], acc[ct], 0, 0, 0);
            }
        }
    }
#pragma unroll
    for (int ct = 0; ct < 4; ++ct) {
        int col = col0 + ct * 16 + lm;
        if (col >= N) continue;
        int rbase = row0 + wave * 16 + lq * 4;
#pragma unroll
        for (int reg = 0; reg < 4; ++reg) {
            C[(size_t)(rbase + reg) * N + col] = acc[ct][reg];
        }
    }
}

// out-proj: x[m][n] += sc[m]*sum_k g[m][k]*(W*nw)[n][k]; split-K 4, BK=64.
// EXACT R7/R4/R11 version, natural block map.
__global__ void __launch_bounds__(256) gemm_outs(const unsigned short* __restrict__ Ghg,
        const unsigned short* __restrict__ Glg, const float* __restrict__ rowssq,
        const unsigned short* __restrict__ Bhi, const unsigned short* __restrict__ Blo,
        float* __restrict__ x) {
    __shared__ __align__(16) unsigned short Ah[64 * 72];
    __shared__ __align__(16) unsigned short Al[64 * 72];
    __shared__ __align__(16) unsigned short Bh[64 * 72];
    __shared__ __align__(16) unsigned short Bl[64 * 72];
    const int tid = threadIdx.x;
    const int col0 = blockIdx.x * 64;
    const int row0 = blockIdx.y * 64;
    const int kbase = blockIdx.z * 128;
    const int sar = tid >> 2, sas = (tid & 3) * 16;
    const unsigned short* ahptr = Ghg + (size_t)(row0 + sar) * DIN_ + kbase + sas;
    const unsigned short* alptr = Glg + (size_t)(row0 + sar) * DIN_ + kbase + sas;
    const unsigned short* bhptr = Bhi + (size_t)(col0 + sar) * DIN_ + kbase + sas;
    const unsigned short* blptr = Blo + (size_t)(col0 + sar) * DIN_ + kbase + sas;

    short8 pah0 = *(const short8*)ahptr, pah1 = *(const short8*)(ahptr + 8);
    short8 pal0 = *(const short8*)alptr, pal1 = *(const short8*)(alptr + 8);
    short8 pbh0 = *(const short8*)bhptr, pbh1 = *(const short8*)(bhptr + 8);
    short8 pbl0 = *(const short8*)blptr, pbl1 = *(const short8*)(blptr + 8);

    const int wave = tid >> 6, lane = tid & 63;
    const int lq = lane >> 4, lm = lane & 15;
    f32x4 acc[4] = {};
    for (int s = 0; s < 2; ++s) {
        __syncthreads();
        *(short8*)&Ah[sar * 72 + sas] = pah0;
        *(short8*)&Ah[sar * 72 + sas + 8] = pah1;
        *(short8*)&Al[sar * 72 + sas] = pal0;
        *(short8*)&Al[sar * 72 + sas + 8] = pal1;
        *(short8*)&Bh[sar * 72 + sas] = pbh0;
        *(short8*)&Bh[sar * 72 + sas + 8] = pbh1;
        *(short8*)&Bl[sar * 72 + sas] = pbl0;
        *(short8*)&Bl[sar * 72 + sas + 8] = pbl1;
        __syncthreads();
        if (s + 1 < 2) {
            int ko = 64;
            pah0 = *(const short8*)(ahptr + ko); pah1 = *(const short8*)(ahptr + ko + 8);
            pal0 = *(const short8*)(alptr + ko); pal1 = *(const short8*)(alptr + ko + 8);
            pbh0 = *(const short8*)(bhptr + ko); pbh1 = *(const short8*)(bhptr + ko + 8);
            pbl0 = *(const short8*)(blptr + ko); pbl1 = *(const short8*)(blptr + ko + 8);
        }
#pragma unroll
        for (int k32 = 0; k32 < 2; ++k32) {
            const int kof = k32 * 32 + lq * 8;
            short8 bh[4], bl[4];
#pragma unroll
            for (int ct = 0; ct < 4; ++ct) {
                bh[ct] = *(const short8*)&Bh[(ct * 16 + lm) * 72 + kof];
                bl[ct] = *(const short8*)&Bl[(ct * 16 + lm) * 72 + kof];
            }
            short8 ah = *(const short8*)&Ah[(wave * 16 + lm) * 72 + kof];
            short8 al = *(const short8*)&Al[(wave * 16 + lm) * 72 + kof];
#pragma unroll
            for (int ct = 0; ct < 4; ++ct) {
                acc[ct] = __builtin_amdgcn_mfma_f32_16x16x32_bf16(ah, bh[ct], acc[ct], 0, 0, 0);
                acc[ct] = __builtin_amdgcn_mfma_f32_16x16x32_bf16(ah, bl[ct], acc[ct], 0, 0, 0);
                acc[ct] = __builtin_amdgcn_mfma_f32_16x16x32_bf16(al, bh[ct], acc[ct], 0, 0, 0);
            }
        }
    }
    {
        int rbase = row0 + wave * 16 + lq * 4;
        float sc[4];
#pragma unroll
        for (int reg = 0; reg < 4; ++reg)
            sc[reg] = rsqrtf(rowssq[rbase + reg] * (1.f / DIN_) + EPS_);
#pragma unroll
        for (int ct = 0; ct < 4; ++ct) {
            int col = col0 + ct * 16 + lm;
#pragma unroll
            for (int reg = 0; reg < 4; ++reg) {
                atomicAdd(&x[(size_t)(rbase + reg) * D_ + col], sc[reg] * acc[ct][reg]);
            }
        }
    }
}

// Fused SSM part A — EXACT R4 version (frozen).
__global__ void __launch_bounds__(512) k_ssmA(const float* __restrict__ zx,
        const float* __restrict__ cw, const float* __restrict__ cb,
        const float* __restrict__ dtbias, const float* __restrict__ Alog,
        const float* __restrict__ Dp,
        float* __restrict__ Sbuf, float* __restrict__ decay,
        float* __restrict__ Ctil, float* __restrict__ y, float* __restrict__ rowssq) {
    __shared__ float U[64][65];
    __shared__ float V[64][65];
    __shared__ float W[64][65];
    __shared__ float sdt[64], cs[64], wj[64];
    const int c = blockIdx.x, bh = blockIdx.y;
    const int b = bh >> 3, h = bh & 7;
    const int l0 = c << 6;
    const int tid = threadIdx.x, wid8 = tid >> 6, lane = tid & 63;

    if (h == 0 && tid < 64) rowssq[b * L_LEN + l0 + tid] = 0.f;

    const int chx = h * P_ + lane;
    const int chb = DIN_ + lane;
    const int chc = DIN_ + NSTATE_ + lane;
    float wx0 = cw[chx * 4], wx1 = cw[chx * 4 + 1], wx2 = cw[chx * 4 + 2], wx3 = cw[chx * 4 + 3];
    float wb0 = cw[chb * 4], wb1 = cw[chb * 4 + 1], wb2 = cw[chb * 4 + 2], wb3 = cw[chb * 4 + 3];
    float wc0 = cw[chc * 4], wc1 = cw[chc * 4 + 1], wc2 = cw[chc * 4 + 2], wc3 = cw[chc * 4 + 3];
    float bx = cb[chx], bb = cb[chb], bc = cb[chc];

    for (int r = 0; r < 64; r += 8) {
        int j = r + wid8;
        int l = l0 + j;
        float ax = bx, ab = bb, ac = bc;
#pragma unroll
        for (int k = 0; k < 4; ++k) {
            int t = l - 3 + k;
            if (t >= 0) {
                const float* row = zx + (size_t)(b * L_LEN + t) * DPROJ_;
                float wxk = (k == 0) ? wx0 : (k == 1) ? wx1 : (k == 2) ? wx2 : wx3;
                float wbk = (k == 0) ? wb0 : (k == 1) ? wb1 : (k == 2) ? wb2 : wb3;
                float wck = (k == 0) ? wc0 : (k == 1) ? wc1 : (k == 2) ? wc2 : wc3;
                ax += wxk * row[DIN_ + chx];
                ab += wbk * row[DIN_ + chb];
                ac += wck * row[DIN_ + chc];
            }
        }
        U[j][lane] = siluf(ax);
        V[j][lane] = siluf(ab);
        W[j][lane] = siluf(ac);
    }
    if (tid < 64) {
        float xv = zx[(size_t)(b * L_LEN + l0 + tid) * DPROJ_ + (DPROJ_ - H_) + h] + dtbias[h];
        float sp = fmaxf(xv, 0.f) + log1pf(__expf(-fabsf(xv)));
        sdt[tid] = sp;
        float v = sp * (-__expf(Alog[h]));
#pragma unroll
        for (int off = 1; off < 64; off <<= 1) {
            float t = __shfl_up(v, off, 64);
            if (tid >= off) v += t;
        }
        cs[tid] = v;
        float tot = __shfl(v, 63, 64);
        wj[tid] = __expf(tot - v) * sp;
        if (tid == 63) decay[bh * NCH_ + c] = __expf(tot);
    }
    __syncthreads();

    const int t4 = (tid & 15) * 4;
    const int r4 = ((tid >> 4) & 15) * 4;
    const size_t sbase = (size_t)(bh * NCH_ + c) * 4096;

    if (tid < 256) {
        float acc[4][4] = {};
        for (int j = 0; j < 64; ++j) {
            float w = wj[j];
            float4 xv = *(const float4*)&U[j][r4];
            float4 bv = *(const float4*)&V[j][t4];
            float xw[4] = {xv.x * w, xv.y * w, xv.z * w, xv.w * w};
#pragma unroll
            for (int ii = 0; ii < 4; ++ii) {
                acc[ii][0] += xw[ii] * bv.x;
                acc[ii][1] += xw[ii] * bv.y;
                acc[ii][2] += xw[ii] * bv.z;
                acc[ii][3] += xw[ii] * bv.w;
            }
        }
#pragma unroll
        for (int ii = 0; ii < 4; ++ii) {
            float4 v = {acc[ii][0], acc[ii][1], acc[ii][2], acc[ii][3]};
            *(float4*)&Sbuf[sbase + (size_t)(r4 + ii) * 64 + t4] = v;
        }
    }
    for (int r = 0; r < 64; r += 8) {
        int ii = r + wid8;
        Ctil[sbase + ii * 64 + lane] = __expf(cs[ii]) * W[ii][lane];
    }
    float wt[4][4];
    if (tid < 256) {
        float g[4][4] = {};
        for (int ng = 0; ng < 64; ng += 4) {
            float4 cf[4], bf[4];
#pragma unroll
            for (int ii = 0; ii < 4; ++ii) cf[ii] = *(const float4*)&W[r4 + ii][ng];
#pragma unroll
            for (int jj = 0; jj < 4; ++jj) bf[jj] = *(const float4*)&V[t4 + jj][ng];
#pragma unroll
            for (int ii = 0; ii < 4; ++ii)
#pragma unroll
                for (int jj = 0; jj < 4; ++jj)
                    g[ii][jj] += cf[ii].x * bf[jj].x + cf[ii].y * bf[jj].y +
                                 cf[ii].z * bf[jj].z + cf[ii].w * bf[jj].w;
        }
#pragma unroll
        for (int ii = 0; ii < 4; ++ii) {
            int i = r4 + ii;
            float csi = cs[i];
#pragma unroll
            for (int jj = 0; jj < 4; ++jj) {
                int j = t4 + jj;
                wt[ii][jj] = (j <= i) ? __expf(fminf(csi - cs[j], 0.f)) * sdt[j] * g[ii][jj] : 0.f;
            }
        }
    }
    __syncthreads();
    if (tid < 256) {
#pragma unroll
        for (int jj = 0; jj < 4; ++jj) {
            float4 v = {wt[0][jj], wt[1][jj], wt[2][jj], wt[3][jj]};
            *(float4*)&V[t4 + jj][r4] = v;
        }
    }
    __syncthreads();
    if (tid < 256) {
        float acc[4][4] = {};
        for (int j = 0; j < 64; ++j) {
            float4 wv = *(const float4*)&V[j][r4];
            float4 xv = *(const float4*)&U[j][t4];
            float ws[4] = {wv.x, wv.y, wv.z, wv.w};
#pragma unroll
            for (int ii = 0; ii < 4; ++ii) {
                acc[ii][0] += ws[ii] * xv.x;
                acc[ii][1] += ws[ii] * xv.y;
                acc[ii][2] += ws[ii] * xv.z;
                acc[ii][3] += ws[ii] * xv.w;
            }
        }
        float Dh = Dp[h];
#pragma unroll
        for (int ii = 0; ii < 4; ++ii) {
            float4 xv = *(const float4*)&U[r4 + ii][t4];
            float4 v = {acc[ii][0] + Dh * xv.x, acc[ii][1] + Dh * xv.y,
                        acc[ii][2] + Dh * xv.z, acc[ii][3] + Dh * xv.w};
            *(float4*)&y[(size_t)(b * L_LEN + l0 + r4 + ii) * DIN_ + h * P_ + t4] = v;
        }
    }
}

// inter-chunk + prefix scan + gating — R11 version (XCD-grouping remap, −10.5us).
__global__ void __launch_bounds__(512) k_inter(const float* __restrict__ Sbuf,
        const float* __restrict__ Ctil, const float* __restrict__ decay,
        const float* __restrict__ zx, const float* __restrict__ y,
        unsigned short* __restrict__ gh, unsigned short* __restrict__ gl,
        float* __restrict__ rowssq) {
    __shared__ float Sm[64][65];
    __shared__ float Cm[64][65];
    const int lin = blockIdx.x + NCH_ * blockIdx.y;   // 0..255
    const int xg = lin & 7, kg = lin >> 3;            // kg 0..31
    const int bh = xg + 8 * (kg >> 4);
    const int c = kg & 15;
    const int b = bh >> 3, h = bh & 7;
    const int l0 = c << 6;
    const int tid = threadIdx.x, wid8 = tid >> 6, lane = tid & 63;
    const size_t bhbase = (size_t)bh * NCH_ * 4096;

    float dec[NCH_];
#pragma unroll
    for (int k = 0; k < NCH_; ++k) dec[k] = decay[bh * NCH_ + k];

    float acc8[8] = {};
    float wgt = 1.f;
    for (int cp = c - 1; cp >= 0; --cp) {
        const float* src = Sbuf + bhbase + (size_t)cp * 4096;
#pragma unroll
        for (int i = 0; i < 8; ++i) acc8[i] += wgt * src[i * 512 + tid];
        wgt *= dec[cp];
    }
#pragma unroll
    for (int i = 0; i < 8; ++i) Sm[i * 8 + wid8][lane] = acc8[i];

    const size_t base = bhbase + (size_t)c * 4096;
    for (int r = 0; r < 64; r += 8) {
        int pp = r + wid8;
        Cm[pp][lane] = Ctil[base + pp * 64 + lane];
    }
    __syncthreads();
    const int t4 = (tid & 15) * 4;
    const int r4 = ((tid >> 4) & 15) * 4;
    if (tid < 256) {
        float acc[4][4] = {};
        if (c > 0) {
            for (int ng = 0; ng < 64; ng += 4) {
                float4 cf[4], sf[4];
#pragma unroll
                for (int ii = 0; ii < 4; ++ii) cf[ii] = *(const float4*)&Cm[r4 + ii][ng];
#pragma unroll
                for (int pp = 0; pp < 4; ++pp) sf[pp] = *(const float4*)&Sm[t4 + pp][ng];
#pragma unroll
                for (int ii = 0; ii < 4; ++ii)
#pragma unroll
                    for (int pp = 0; pp < 4; ++pp)
                        acc[ii][pp] += cf[ii].x * sf[pp].x + cf[ii].y * sf[pp].y +
                                       cf[ii].z * sf[pp].z + cf[ii].w * sf[pp].w;
            }
        }
        float ssq[4];
#pragma unroll
        for (int ii = 0; ii < 4; ++ii) {
            int row = b * L_LEN + l0 + r4 + ii;
            const float* yr = &y[(size_t)row * DIN_ + h * P_ + t4];
            const float* zr = &zx[(size_t)row * DPROJ_ + h * P_ + t4];
            float4 v = *(const float4*)yr;
            float4 z = *(const float4*)zr;
            v.x = (v.x + acc[ii][0]) * siluf(z.x);
            v.y = (v.y + acc[ii][1]) * siluf(z.y);
            v.z = (v.z + acc[ii][2]) * siluf(z.z);
            v.w = (v.w + acc[ii][3]) * siluf(z.w);
            unsigned short h0 = f2bf(v.x), h1 = f2bf(v.y), h2 = f2bf(v.z), h3 = f2bf(v.w);
            us4 hv = {h0, h1, h2, h3};
            us4 lv = {f2bf(v.x - bf2f(h0)), f2bf(v.y - bf2f(h1)),
                      f2bf(v.z - bf2f(h2)), f2bf(v.w - bf2f(h3))};
            *(us4*)&gh[(size_t)row * DIN_ + h * P_ + t4] = hv;
            *(us4*)&gl[(size_t)row * DIN_ + h * P_ + t4] = lv;
            ssq[ii] = v.x * v.x + v.y * v.y + v.z * v.z + v.w * v.w;
        }
#pragma unroll
        for (int o = 1; o < 16; o <<= 1) {
#pragma unroll
            for (int ii = 0; ii < 4; ++ii) ssq[ii] += __shfl_xor(ssq[ii], o, 64);
        }
        if ((tid & 15) == 0) {
#pragma unroll
            for (int ii = 0; ii < 4; ++ii)
                atomicAdd(&rowssq[b * L_LEN + l0 + r4 + ii], ssq[ii]);
        }
    }
}

// pooling partial pass (32 blocks)
__global__ void __launch_bounds__(256) k_pool1(const float* __restrict__ x,
        float* __restrict__ psum, float* __restrict__ pmax) {
    int s = blockIdx.x, b = blockIdx.y, t = threadIdx.x;
    const float* xb = x + ((size_t)b * L_LEN + s * 64) * D_ + t;
    float sm = 0.f, mx = -INFINITY;
    for (int l = 0; l < 64; l += 4) {
        float v0 = xb[(size_t)l * D_];
        float v1 = xb[(size_t)(l + 1) * D_];
        float v2 = xb[(size_t)(l + 2) * D_];
        float v3 = xb[(size_t)(l + 3) * D_];
        sm += v0 + v1 + v2 + v3;
        mx = fmaxf(mx, fmaxf(fmaxf(v0, v1), fmaxf(v2, v3)));
    }
    psum[(b * 16 + s) * 256 + t] = sm;
    pmax[(b * 16 + s) * 256 + t] = mx;
}

// finalize & classifier head (2 blocks x 1024 threads)
__global__ void __launch_bounds__(1024) k_pool2(const float* __restrict__ psum,
                           const float* __restrict__ pmax,
                           const float* __restrict__ pw, const float* __restrict__ pb,
                           const float* __restrict__ c1w, const float* __restrict__ c1b,
                           const float* __restrict__ c2w, const float* __restrict__ c2b,
                           float* __restrict__ out) {
    __shared__ float sp[256], s1[256], s2[128];
    int b = blockIdx.x, tid = threadIdx.x;
    if (tid < 256) {
        float ss = 0.f, mm = -INFINITY;
#pragma unroll
        for (int s = 0; s < 16; ++s) {
            ss += psum[(b * 16 + s) * 256 + tid];
            mm = fmaxf(mm, pmax[(b * 16 + s) * 256 + tid]);
        }
        sp[tid] = (ss * (1.f / L_LEN) + mm) * 0.5f;
    }
    __syncthreads();
    {
        int o = tid >> 2, part = tid & 3;
        const float* wrow = pw + (size_t)o * 256 + part * 64;
        const float* sv = sp + part * 64;
        float acc = 0.f;
        for (int d = 0; d < 64; d += 4) {
            float4 w4 = *(const float4*)(wrow + d);
            float4 x4 = *(const float4*)(sv + d);
            acc += w4.x * x4.x + w4.y * x4.y + w4.z * x4.z + w4.w * x4.w;
        }
        acc += __shfl_xor(acc, 1, 64);
        acc += __shfl_xor(acc, 2, 64);
        if (part == 0) s1[o] = geluf(acc + pb[o]);
    }
    __syncthreads();
    {
        int o = tid >> 3, part = tid & 7;
        const float* wrow = c1w + (size_t)o * 256 + part * 32;
        const float* sv = s1 + part * 32;
        float acc = 0.f;
        for (int d = 0; d < 32; d += 4) {
            float4 w4 = *(const float4*)(wrow + d);
            float4 x4 = *(const float4*)(sv + d);
            acc += w4.x * x4.x + w4.y * x4.y + w4.z * x4.z + w4.w * x4.w;
        }
        acc += __shfl_xor(acc, 1, 64);
        acc += __shfl_xor(acc, 2, 64);
        acc += __shfl_xor(acc, 4, 64);
        if (part == 0) s2[o] = geluf(acc + c1b[o]);
    }
    __syncthreads();
    if (tid < 2) {
        float a = c2b[tid];
        for (int d = 0; d < 128; ++d) a += s2[d] * c2w[tid * 128 + d];
        out[b * NC_ + tid] = a;
    }
}

extern "C" void kernel_launch(void* const* d_in, const int* in_sizes, int n_in,
                              void* d_out, int out_size, void* d_ws, size_t ws_size,
                              hipStream_t stream) {
    const int* ids    = (const int*)d_in[0];
    const float* emb  = (const float*)d_in[1];
    const float* pos  = (const float*)d_in[2];
    const float* Wins = (const float*)d_in[3];
    const float* cw   = (const float*)d_in[4];
    const float* cb   = (const float*)d_in[5];
    const float* dtb  = (const float*)d_in[6];
    const float* Alog = (const float*)d_in[7];
    const float* Dpar = (const float*)d_in[8];
    const float* nw   = (const float*)d_in[9];
    const float* Wout = (const float*)d_in[10];
    const float* pw   = (const float*)d_in[11];
    const float* pb   = (const float*)d_in[12];
    const float* c1w  = (const float*)d_in[13];
    const float* c1b  = (const float*)d_in[14];
    const float* c2w  = (const float*)d_in[15];
    const float* c2b  = (const float*)d_in[16];
    float* out = (float*)d_out;

    const int NWIN = NL_ * DPROJ_ * D_;   // 1187840
    const int NWOUT = NL_ * D_ * DIN_;    // 524288
    const int NG = 1048576;               // 2048*512
    const int NX = 524288;                // 2048*256

    float* ws = (float*)d_ws;
    float* x      = ws;                 // 524288
    float* zx     = x + 524288;         // 2375680
    float* y      = zx + 2375680;       // 1048576
    float* Sbuf   = y + 1048576;        // 1048576
    float* Ctil   = Sbuf + 1048576;     // 1048576
    float* decay  = Ctil + 1048576;     // 256
    float* rowssq = decay + 256;        // 2048
    unsigned short* winh = (unsigned short*)(rowssq + 2048);
    unsigned short* winl = winh + NWIN;
    unsigned short* woh  = winl + NWIN;
    unsigned short* wol  = woh + NWOUT;
    unsigned short* gh   = wol + NWOUT;
    unsigned short* gl   = gh + NG;
    float* psum = (float*)(gl + NG);    // 2*16*256
    float* pmax = psum + 2 * 16 * 256;  // 2*16*256

    const int NPREP = NWIN + NWOUT + NX;
    k_prep<<<(NPREP + 255) / 256, 256, 0, stream>>>(
        Wins, Wout, nw, winh, winl, woh, wol,
        ids, emb, pos, x, NWIN, NWOUT, NX);
    for (int i = 0; i < NL_; ++i) {
        size_t wo_in = (size_t)i * DPROJ_ * D_;
        size_t wo_out = (size_t)i * D_ * DIN_;
        gemm_in<<<dim3(19, 32), 256, 0, stream>>>(
            x, winh + wo_in, winl + wo_in, zx, 2048, DPROJ_, D_);
        k_ssmA<<<dim3(NCH_, 16), 512, 0, stream>>>(
            zx, cw + (size_t)i * CONVDIM_ * 4, cb + (size_t)i * CONVDIM_,
            dtb + i * H_, Alog + i * H_, Dpar + i * H_, Sbuf, decay, Ctil, y, rowssq);
        k_inter<<<dim3(NCH_, 16), 512, 0, stream>>>(Sbuf, Ctil, decay, zx, y, gh, gl, rowssq);
        gemm_outs<<<dim3(4, 32, 4), 256, 0, stream>>>(
            gh, gl, rowssq, woh + wo_out, wol + wo_out, x);
    }
    k_pool1<<<dim3(16, 2), 256, 0, stream>>>(x, psum, pmax);
    k_pool2<<<2, 1024, 0, stream>>>(psum, pmax, pw, pb, c1w, c1b, c2w, c2b, out);
}